// Round 15
// baseline (213.368 us; speedup 1.0000x reference)
//
#include <hip/hip_runtime.h>
#include <math.h>

#define BATCH  2
#define SEQ    2048
#define NH     16
#define DMODEL 1024
#define DHEAD  64
#define NSPLIT 2   // key-splits for attention

typedef short short8 __attribute__((ext_vector_type(8)));
typedef float f32x4 __attribute__((ext_vector_type(4)));

// Q pre-scale: 1/sqrt(64) * log2(e)  -> softmax via exp2
#define QSCALE 0.18033688011112042f

__device__ __forceinline__ ushort f2bf(float f) {
  // round-to-nearest-even f32 -> bf16 (finite inputs only)
  unsigned int u = __builtin_bit_cast(unsigned int, f);
  u = (u + 0x7FFFu + ((u >> 16) & 1u)) >> 16;
  return (ushort)u;
}

__device__ __forceinline__ float bf2f(ushort u) {
  const unsigned int v = ((unsigned int)u) << 16;
  return __builtin_bit_cast(float, v);
}

// pack two f32 -> one u32 of two bf16 (RNE), single HW instruction
__device__ __forceinline__ unsigned int cvtpk(float lo, float hi) {
  unsigned int r;
  asm("v_cvt_pk_bf16_f32 %0, %1, %2" : "=v"(r) : "v"(lo), "v"(hi));
  return r;
}

// gfx950 cross-lane swaps (VALU pipe, 1 instr).
// CORRECTNESS (r11 post-mortem): operands MUST be distinct SSA values —
// copies of one value get register-coalesced and the instruction
// self-swaps (data loss). Butterfly operands are distinct cvt_pk outputs.
// Reductions over copies of one value use __shfl_xor instead.
#define P32SWAP(a, b) \
  asm("v_permlane32_swap_b32 %0, %1" : "+v"(a), "+v"(b))
#define P16SWAP(a, b) \
  asm("v_permlane16_swap_b32 %0, %1" : "+v"(a), "+v"(b))

// ---------------------------------------------------------------------------
// Cast fp32 -> bf16 (r13 verbatim — separate pass is faster than fused, r14).
// ---------------------------------------------------------------------------
__global__ __launch_bounds__(256) void cast_all(
    const float* __restrict__ hs, const float* __restrict__ wq,
    const float* __restrict__ wk, const float* __restrict__ wv,
    const float* __restrict__ wo,
    ushort* __restrict__ hsb, ushort* __restrict__ wqb,
    ushort* __restrict__ wkb, ushort* __restrict__ wvb,
    ushort* __restrict__ wob) {
  const int z = blockIdx.y;
  const float* s = (z == 0) ? hs : (z == 1) ? wq : (z == 2) ? wk
                   : (z == 3) ? wv : wo;
  ushort* d = (z == 0) ? hsb : (z == 1) ? wqb : (z == 2) ? wkb
              : (z == 3) ? wvb : wob;
  const int n = (z == 0) ? BATCH * SEQ * DMODEL : DMODEL * DMODEL;
  const int i = (blockIdx.x * 256 + threadIdx.x) * 8;
  if (i < n) {
    const float4 a = *(const float4*)(s + i);
    const float4 b = *(const float4*)(s + i + 4);
    short8 o;
    o[0] = (short)f2bf(a.x); o[1] = (short)f2bf(a.y);
    o[2] = (short)f2bf(a.z); o[3] = (short)f2bf(a.w);
    o[4] = (short)f2bf(b.x); o[5] = (short)f2bf(b.y);
    o[6] = (short)f2bf(b.z); o[7] = (short)f2bf(b.w);
    *(short8*)(d + i) = o;
  }
}

// ---------------------------------------------------------------------------
// bf16 MFMA GEMM tile body (r13 verbatim): 128x128 tile, BK=32, 512 thr =
// 8 waves (2m x 4n), wave tile 64x32 = 4x2 frags of 16x16x32.
// ---------------------------------------------------------------------------
__device__ __forceinline__ void mfma_gemm_core(
    const ushort* __restrict__ X, const ushort* __restrict__ W,
    f32x4 (&acc)[4][2]) {
  __shared__ ushort Al[128][40];
  __shared__ ushort Bl[128][40];
  const int tid = threadIdx.x;
  const int lane = tid & 63;
  const int w8 = tid >> 6;
  const int wm = w8 >> 2;
  const int wn = w8 & 3;
  const int m16 = lane & 15;
  const int g4 = lane >> 4;
  const int m0 = blockIdx.y << 7;
  const int n0 = blockIdx.x << 7;

  const int srow = tid >> 2;
  const int sseg = (tid & 3) << 3;
  const ushort* ap = X + (size_t)(m0 + srow) * DMODEL + sseg;
  const ushort* wp = W + (size_t)(n0 + srow) * DMODEL + sseg;

  short8 pa = *(const short8*)(ap);
  short8 pb = *(const short8*)(wp);

  for (int kt = 0; kt < DMODEL / 32; ++kt) {
    __syncthreads();
    *(short8*)&Al[srow][sseg] = pa;
    *(short8*)&Bl[srow][sseg] = pb;
    __syncthreads();
    if (kt < DMODEL / 32 - 1) {  // prefetch next tile under the MFMAs
      pa = *(const short8*)(ap + (kt + 1) * 32);
      pb = *(const short8*)(wp + (kt + 1) * 32);
    }
    short8 af[4], bf[2];
#pragma unroll
    for (int mi = 0; mi < 4; ++mi)
      af[mi] = *(const short8*)&Al[(wm << 6) + (mi << 4) + m16][g4 << 3];
#pragma unroll
    for (int ni = 0; ni < 2; ++ni)
      bf[ni] = *(const short8*)&Bl[(wn << 5) + (ni << 4) + m16][g4 << 3];
#pragma unroll
    for (int mi = 0; mi < 4; ++mi)
#pragma unroll
      for (int ni = 0; ni < 2; ++ni)
        acc[mi][ni] = __builtin_amdgcn_mfma_f32_16x16x32_bf16(
            af[mi], bf[ni], acc[mi][ni], 0, 0, 0);
  }
}

// QKV: bf16 out, Q scaled by QSCALE. Grid: (8, M/128, 3)
__global__ __launch_bounds__(512) void qkv_mfma(
    const ushort* __restrict__ X,
    const ushort* __restrict__ wqb, const ushort* __restrict__ wkb,
    const ushort* __restrict__ wvb,
    const float* __restrict__ bq, const float* __restrict__ bk,
    const float* __restrict__ bv,
    ushort* __restrict__ Qb, ushort* __restrict__ Kb,
    ushort* __restrict__ Vb) {
  const int z = blockIdx.z;
  const ushort* W = (z == 0) ? wqb : (z == 1) ? wkb : wvb;
  const float* bias = (z == 0) ? bq : (z == 1) ? bk : bv;
  ushort* Y = (z == 0) ? Qb : (z == 1) ? Kb : Vb;
  const float oscale = (z == 0) ? QSCALE : 1.0f;

  f32x4 acc[4][2];
#pragma unroll
  for (int mi = 0; mi < 4; ++mi)
#pragma unroll
    for (int ni = 0; ni < 2; ++ni) acc[mi][ni] = (f32x4){0.f, 0.f, 0.f, 0.f};
  mfma_gemm_core(X, W, acc);

  const int tid = threadIdx.x;
  const int lane = tid & 63;
  const int w8 = tid >> 6;
  const int wm = w8 >> 2, wn = w8 & 3;
  const int m16 = lane & 15, g4 = lane >> 4;
  const int m0 = blockIdx.y << 7, n0 = blockIdx.x << 7;
#pragma unroll
  for (int ni = 0; ni < 2; ++ni) {
    const int col = n0 + (wn << 5) + (ni << 4) + m16;
    const float bv4 = bias[col];
#pragma unroll
    for (int mi = 0; mi < 4; ++mi)
#pragma unroll
      for (int r = 0; r < 4; ++r) {
        const int row = m0 + (wm << 6) + (mi << 4) + (g4 << 2) + r;
        Y[(size_t)row * DMODEL + col] = f2bf((acc[mi][ni][r] + bv4) * oscale);
      }
  }
}

// O-projection: bf16 in (Ab, wob), fp32 out + bias. Grid: (8, 32, 1)
__global__ __launch_bounds__(512) void oproj_mfma(
    const ushort* __restrict__ X, const ushort* __restrict__ wob,
    const float* __restrict__ bo, float* __restrict__ Y) {
  f32x4 acc[4][2];
#pragma unroll
  for (int mi = 0; mi < 4; ++mi)
#pragma unroll
    for (int ni = 0; ni < 2; ++ni) acc[mi][ni] = (f32x4){0.f, 0.f, 0.f, 0.f};
  mfma_gemm_core(X, wob, acc);

  const int tid = threadIdx.x;
  const int lane = tid & 63;
  const int w8 = tid >> 6;
  const int wm = w8 >> 2, wn = w8 & 3;
  const int m16 = lane & 15, g4 = lane >> 4;
  const int m0 = blockIdx.y << 7, n0 = blockIdx.x << 7;
#pragma unroll
  for (int ni = 0; ni < 2; ++ni) {
    const int col = n0 + (wn << 5) + (ni << 4) + m16;
    const float bv4 = bo[col];
#pragma unroll
    for (int mi = 0; mi < 4; ++mi)
#pragma unroll
      for (int r = 0; r < 4; ++r) {
        const int row = m0 + (wm << 6) + (mi << 4) + (g4 << 2) + r;
        Y[(size_t)row * DMODEL + col] = acc[mi][ni][r] + bv4;
      }
  }
}

// ---------------------------------------------------------------------------
// MFMA flash attention, round 15 = r13 kernel (validated 79 us) split-K2:
// each block covers 1024 keys (split = blockIdx.z&1), emitting per-split-
// NORMALIZED O (same epilogue as r13) plus (m, l) per q-row. Grid doubles
// to 1024 blocks -> 4 blocks/CU (LDS 36.9KB x4 fits 160KB) -> 8 waves/SIMD.
// __launch_bounds__(512,8) caps VGPR at 64 (r13 used 52).
// Grid: (SEQ/128, NH, BATCH*NSPLIT), 512 thr.
// ---------------------------------------------------------------------------
__global__ __launch_bounds__(512, 8) void attn_mfma(
    const ushort* __restrict__ Q, const ushort* __restrict__ K,
    const ushort* __restrict__ V, ushort* __restrict__ Opart,
    float2* __restrict__ ml) {
  __shared__ ushort Klds[2][64][72];
  __shared__ ushort Vlds[2][64][72];

  const int tid = threadIdx.x;
  const int lane = tid & 63;
  const int wv = tid >> 6;      // wave 0..7
  const int m16 = lane & 15;
  const int g4 = lane >> 4;     // 0..3
  const int b = blockIdx.z >> 1;
  const int split = blockIdx.z & 1;
  const int h = blockIdx.y;
  const int q0 = (blockIdx.x << 7) + (wv << 4);  // wave's 16-row q base

  const size_t base = ((size_t)b * SEQ) * DMODEL + h * DHEAD;  // elem offset
  const size_t elems = (size_t)BATCH * SEQ * DMODEL;

  // --- Q fragments (2 k-steps of 32 over DHEAD=64), rows = m16 ---
  short8 qf[2];
  {
    const ushort* qp = Q + base + (size_t)(q0 + m16) * DMODEL + (g4 << 3);
    qf[0] = *(const short8*)(qp);
    qf[1] = *(const short8*)(qp + 32);
  }

  f32x4 oacc[4];  // [dt]: col d = dt*16+m16, rows q = 4g4 + r
#pragma unroll
  for (int dt = 0; dt < 4; ++dt) oacc[dt] = (f32x4){0.f, 0.f, 0.f, 0.f};
  float mrow = -1e30f;  // running max for q = m16 (log2 domain)
  float lsum = 0.f;     // lane-partial denominator

  // staging map: 512 threads, key = tid>>3 (64), seg = tid&7; this split's
  // keys start at split*1024.
  const int skey = tid >> 3;
  const int sseg = tid & 7;
  const ushort* kgp =
      K + base + (size_t)(split * 1024 + skey) * DMODEL + (sseg << 3);
  const ushort* vgp =
      V + base + (size_t)(split * 1024 + skey) * DMODEL + (sseg << 3);
  const int vswz_key = skey ^ (sseg << 3);  // conflict-free u16 scatter

  // T14: tile-0 loads issued long before first use
  short8 kvec = *(const short8*)(kgp);
  short8 vvec = *(const short8*)(vgp);

  int p = 0;
  for (int kt = 0; kt < 1024 / 64; ++kt) {
    // stage tile kt into buffer p
    *(short8*)&Klds[p][skey][sseg << 3] = kvec;
#pragma unroll
    for (int i = 0; i < 8; ++i)
      Vlds[p][(sseg << 3) + i][vswz_key] = ((const ushort*)&vvec)[i];
    __syncthreads();  // the only barrier per tile (dbuf)
    // T14: issue next tile's global loads; latency hides under compute
    if (kt + 1 < 1024 / 64) {
      const size_t koff = (size_t)(kt + 1) * 64 * DMODEL;
      kvec = *(const short8*)(kgp + koff);
      vvec = *(const short8*)(vgp + koff);
    }

    // --- S^T = K * Q^T : s[kt2][r] = S[key=16*kt2+4*g4+r][q=m16] ---
    f32x4 s[4];
#pragma unroll
    for (int kt2 = 0; kt2 < 4; ++kt2) s[kt2] = (f32x4){0.f, 0.f, 0.f, 0.f};
    __builtin_amdgcn_s_setprio(1);
#pragma unroll
    for (int ks = 0; ks < 2; ++ks) {
#pragma unroll
      for (int kt2 = 0; kt2 < 4; ++kt2) {
        const short8 kf =
            *(const short8*)&Klds[p][(kt2 << 4) + m16][(ks << 5) + (g4 << 3)];
        s[kt2] =
            __builtin_amdgcn_mfma_f32_16x16x32_bf16(kf, qf[ks], s[kt2], 0, 0, 0);
      }
    }
    __builtin_amdgcn_s_setprio(0);

    // --- online softmax for q = m16 (exp2 domain) ---
    float t0 = fmaxf(fmaxf(s[0][0], s[0][1]), fmaxf(s[0][2], s[0][3]));
    float t1 = fmaxf(fmaxf(s[1][0], s[1][1]), fmaxf(s[1][2], s[1][3]));
    float t2 = fmaxf(fmaxf(s[2][0], s[2][1]), fmaxf(s[2][2], s[2][3]));
    float t3 = fmaxf(fmaxf(s[3][0], s[3][1]), fmaxf(s[3][2], s[3][3]));
    float tred = fmaxf(fmaxf(t0, t1), fmaxf(t2, t3));
    tred = fmaxf(tred, __shfl_xor(tred, 16));
    tred = fmaxf(tred, __shfl_xor(tred, 32));
    // T13 defer-max: only rescale when the max grew by more than 8
    if (!__all(tred <= mrow + 8.0f)) {
      const float mnew = fmaxf(mrow, tred);
      const float corr = exp2f(mrow - mnew);
      lsum *= corr;
      const float cb0 = __shfl(corr, (g4 << 2) + 0);
      const float cb1 = __shfl(corr, (g4 << 2) + 1);
      const float cb2 = __shfl(corr, (g4 << 2) + 2);
      const float cb3 = __shfl(corr, (g4 << 2) + 3);
#pragma unroll
      for (int dt = 0; dt < 4; ++dt) {
        oacc[dt][0] *= cb0; oacc[dt][1] *= cb1;
        oacc[dt][2] *= cb2; oacc[dt][3] *= cb3;
      }
      mrow = mnew;
    }
    float ps = 0.f;
#pragma unroll
    for (int kt2 = 0; kt2 < 4; ++kt2)
#pragma unroll
      for (int r = 0; r < 4; ++r) {
        const float pv = exp2f(s[kt2][r] - mrow);
        s[kt2][r] = pv;
        ps += pv;
      }
    lsum += ps;

    // --- P -> PV A-fragment, fully in registers (validated r12/r13) ---
    unsigned int W0 = cvtpk(s[0][0], s[0][1]);
    unsigned int W1 = cvtpk(s[0][2], s[0][3]);
    unsigned int W2 = cvtpk(s[1][0], s[1][1]);
    unsigned int W3 = cvtpk(s[1][2], s[1][3]);
    unsigned int W4 = cvtpk(s[2][0], s[2][1]);
    unsigned int W5 = cvtpk(s[2][2], s[2][3]);
    unsigned int W6 = cvtpk(s[3][0], s[3][1]);
    unsigned int W7 = cvtpk(s[3][2], s[3][3]);
    P32SWAP(W0, W2);
    P32SWAP(W1, W3);
    P32SWAP(W4, W6);
    P32SWAP(W5, W7);
    P16SWAP(W0, W2);
    P16SWAP(W1, W3);
    P16SWAP(W4, W6);
    P16SWAP(W5, W7);
    union { unsigned int u[4]; short8 v; } u0, u1;
    u0.u[0] = W0; u0.u[1] = W1; u0.u[2] = W2; u0.u[3] = W3;
    u1.u[0] = W4; u1.u[1] = W5; u1.u[2] = W6; u1.u[3] = W7;

    // --- O += P * V ---
    __builtin_amdgcn_s_setprio(1);
#pragma unroll
    for (int dt = 0; dt < 4; ++dt) {
      const int d = (dt << 4) + m16;
      const int swz = (d >> 3) << 3;
      const short8 vf0 = *(const short8*)&Vlds[p][d][(g4 << 3) ^ swz];
      oacc[dt] = __builtin_amdgcn_mfma_f32_16x16x32_bf16(
          u0.v, vf0, oacc[dt], 0, 0, 0);
      const short8 vf1 = *(const short8*)&Vlds[p][d][(32 + (g4 << 3)) ^ swz];
      oacc[dt] = __builtin_amdgcn_mfma_f32_16x16x32_bf16(
          u1.v, vf1, oacc[dt], 0, 0, 0);
    }
    __builtin_amdgcn_s_setprio(0);
    p ^= 1;
  }

  // --- epilogue: reduce lsum, normalize (per-split), store O + (m,l) ---
  lsum += __shfl_xor(lsum, 16);
  lsum += __shfl_xor(lsum, 32);
  // lanes 0..15 store (m, l) for q-rows q0..q0+15 of this (split,b,h)
  if (lane < 16) {
    ml[(((size_t)split * BATCH + b) * NH + h) * SEQ + q0 + lane] =
        make_float2(mrow, lsum);
  }
  const float inv = 1.0f / lsum;  // for q = m16, in all 4 g4 copies
  const float inv0 = __shfl(inv, (g4 << 2) + 0);
  const float inv1 = __shfl(inv, (g4 << 2) + 1);
  const float inv2 = __shfl(inv, (g4 << 2) + 2);
  const float inv3 = __shfl(inv, (g4 << 2) + 3);
  const float invr[4] = {inv0, inv1, inv2, inv3};
  ushort* obase = Opart + (size_t)split * elems;
#pragma unroll
  for (int r = 0; r < 4; ++r) {
    const size_t row = (size_t)(q0 + (g4 << 2) + r);
    ushort* op = obase + ((size_t)b * SEQ + row) * DMODEL + h * DHEAD + m16;
#pragma unroll
    for (int dt = 0; dt < 4; ++dt) op[dt << 4] = f2bf(oacc[dt][r] * invr[r]);
  }
}

// ---------------------------------------------------------------------------
// Merge the two per-split-normalized partials:
//   w_i = l_i * 2^(m_i - m) / sum,  O = w0*O0 + w1*O1   (exp2 domain)
// Writes IN PLACE over split-0's buffer (thread-local idx-for-idx: race-free,
// and attn rewrites the buffer each call -> replay-deterministic).
// ---------------------------------------------------------------------------
__global__ __launch_bounds__(256) void attn_merge(
    ushort* __restrict__ Opart, const float2* __restrict__ ml) {
  const size_t elems = (size_t)BATCH * SEQ * DMODEL;
  const size_t e0 = ((size_t)blockIdx.x * 256 + threadIdx.x) * 8;
  if (e0 >= elems) return;
  const int b = (int)(e0 / ((size_t)SEQ * DMODEL));
  const size_t rem = e0 % ((size_t)SEQ * DMODEL);
  const int s = (int)(rem / DMODEL);
  const int d = (int)(rem % DMODEL);
  const int h = d >> 6;

  const float2 ml0 = ml[(((size_t)0 * BATCH + b) * NH + h) * SEQ + s];
  const float2 ml1 = ml[(((size_t)1 * BATCH + b) * NH + h) * SEQ + s];
  const float m = fmaxf(ml0.x, ml1.x);
  const float a0 = ml0.y * exp2f(ml0.x - m);
  const float a1 = ml1.y * exp2f(ml1.x - m);
  const float inv = 1.0f / (a0 + a1);
  const float w0 = a0 * inv;
  const float w1 = a1 * inv;

  const short8 o0 = *(const short8*)(Opart + e0);
  const short8 o1 = *(const short8*)(Opart + elems + e0);
  short8 o;
#pragma unroll
  for (int j = 0; j < 8; ++j) {
    const float v =
        w0 * bf2f((ushort)o0[j]) + w1 * bf2f((ushort)o1[j]);
    o[j] = (short)f2bf(v);
  }
  *(short8*)(Opart + e0) = o;
}

// ---------------------------------------------------------------------------
extern "C" void kernel_launch(void* const* d_in, const int* in_sizes, int n_in,
                              void* d_out, int out_size, void* d_ws,
                              size_t ws_size, hipStream_t stream) {
  const float* hs = (const float*)d_in[0];
  const float* wq = (const float*)d_in[1];
  const float* bq = (const float*)d_in[2];
  const float* wk = (const float*)d_in[3];
  const float* bk = (const float*)d_in[4];
  const float* wv = (const float*)d_in[5];
  const float* bv = (const float*)d_in[6];
  const float* wo = (const float*)d_in[7];
  const float* bo = (const float*)d_in[8];
  float* out = (float*)d_out;

  // ws layout (ushort elems): hsb 4M | wqb/wkb/wvb/wob 1M each | Qb/Kb/Vb 4M
  // | Opart 8M (2 splits; split 0 doubles as merged Ab) | ml 1MB
  // total = 28M ushorts (56 MiB) + 1 MiB = 57 MiB (r3 proved >= 64 MiB ws)
  const size_t elems = (size_t)BATCH * SEQ * DMODEL;  // 4M
  const size_t welems = (size_t)DMODEL * DMODEL;      // 1M
  ushort* hsb = (ushort*)d_ws;
  ushort* wqb = hsb + elems;
  ushort* wkb = wqb + welems;
  ushort* wvb = wkb + welems;
  ushort* wob = wvb + welems;
  ushort* Qb = wob + welems;
  ushort* Kb = Qb + elems;
  ushort* Vb = Kb + elems;
  ushort* Opart = Vb + elems;                      // 2 * elems ushorts
  float2* ml = (float2*)(Opart + NSPLIT * elems);  // NSPLIT*B*NH*SEQ float2

  cast_all<<<dim3((int)(elems / (256 * 8)), 5, 1), 256, 0, stream>>>(
      hs, wq, wk, wv, wo, hsb, wqb, wkb, wvb, wob);
  qkv_mfma<<<dim3(DMODEL / 128, (BATCH * SEQ) / 128, 3), 512, 0, stream>>>(
      hsb, wqb, wkb, wvb, bq, bk, bv, Qb, Kb, Vb);
  attn_mfma<<<dim3(SEQ / 128, NH, BATCH * NSPLIT), 512, 0, stream>>>(
      Qb, Kb, Vb, Opart, ml);
  attn_merge<<<dim3((int)(elems / (256 * 8)), 1, 1), 256, 0, stream>>>(
      Opart, ml);
  oproj_mfma<<<dim3(DMODEL / 128, (BATCH * SEQ) / 128, 1), 512, 0, stream>>>(
      Opart, wob, bo, out);
}

// Round 16
// 146.256 us; speedup vs baseline: 1.4589x; 1.4589x over previous
//
#include <hip/hip_runtime.h>
#include <math.h>

#define BATCH  2
#define SEQ    2048
#define NH     16
#define DMODEL 1024
#define DHEAD  64
#define NSPLIT 2   // key-splits for attention

typedef short short8 __attribute__((ext_vector_type(8)));
typedef float f32x4 __attribute__((ext_vector_type(4)));

// Q pre-scale: 1/sqrt(64) * log2(e)  -> softmax via exp2
#define QSCALE 0.18033688011112042f

__device__ __forceinline__ ushort f2bf(float f) {
  // round-to-nearest-even f32 -> bf16 (finite inputs only)
  unsigned int u = __builtin_bit_cast(unsigned int, f);
  u = (u + 0x7FFFu + ((u >> 16) & 1u)) >> 16;
  return (ushort)u;
}

__device__ __forceinline__ float bf2f(ushort u) {
  const unsigned int v = ((unsigned int)u) << 16;
  return __builtin_bit_cast(float, v);
}

// pack two f32 -> one u32 of two bf16 (RNE), single HW instruction
__device__ __forceinline__ unsigned int cvtpk(float lo, float hi) {
  unsigned int r;
  asm("v_cvt_pk_bf16_f32 %0, %1, %2" : "=v"(r) : "v"(lo), "v"(hi));
  return r;
}

// gfx950 cross-lane swaps (VALU pipe, 1 instr).
// CORRECTNESS (r11 post-mortem): operands MUST be distinct SSA values —
// copies of one value get register-coalesced and the instruction
// self-swaps (data loss). Butterfly operands are distinct cvt_pk outputs.
// Reductions over copies of one value use __shfl_xor instead.
#define P32SWAP(a, b) \
  asm("v_permlane32_swap_b32 %0, %1" : "+v"(a), "+v"(b))
#define P16SWAP(a, b) \
  asm("v_permlane16_swap_b32 %0, %1" : "+v"(a), "+v"(b))

// ---------------------------------------------------------------------------
// Cast fp32 -> bf16 (r13 verbatim — separate pass is faster than fused, r14).
// ---------------------------------------------------------------------------
__global__ __launch_bounds__(256) void cast_all(
    const float* __restrict__ hs, const float* __restrict__ wq,
    const float* __restrict__ wk, const float* __restrict__ wv,
    const float* __restrict__ wo,
    ushort* __restrict__ hsb, ushort* __restrict__ wqb,
    ushort* __restrict__ wkb, ushort* __restrict__ wvb,
    ushort* __restrict__ wob) {
  const int z = blockIdx.y;
  const float* s = (z == 0) ? hs : (z == 1) ? wq : (z == 2) ? wk
                   : (z == 3) ? wv : wo;
  ushort* d = (z == 0) ? hsb : (z == 1) ? wqb : (z == 2) ? wkb
              : (z == 3) ? wvb : wob;
  const int n = (z == 0) ? BATCH * SEQ * DMODEL : DMODEL * DMODEL;
  const int i = (blockIdx.x * 256 + threadIdx.x) * 8;
  if (i < n) {
    const float4 a = *(const float4*)(s + i);
    const float4 b = *(const float4*)(s + i + 4);
    short8 o;
    o[0] = (short)f2bf(a.x); o[1] = (short)f2bf(a.y);
    o[2] = (short)f2bf(a.z); o[3] = (short)f2bf(a.w);
    o[4] = (short)f2bf(b.x); o[5] = (short)f2bf(b.y);
    o[6] = (short)f2bf(b.z); o[7] = (short)f2bf(b.w);
    *(short8*)(d + i) = o;
  }
}

// ---------------------------------------------------------------------------
// bf16 MFMA GEMM tile body (r13 verbatim): 128x128 tile, BK=32, 512 thr =
// 8 waves (2m x 4n), wave tile 64x32 = 4x2 frags of 16x16x32.
// ---------------------------------------------------------------------------
__device__ __forceinline__ void mfma_gemm_core(
    const ushort* __restrict__ X, const ushort* __restrict__ W,
    f32x4 (&acc)[4][2]) {
  __shared__ ushort Al[128][40];
  __shared__ ushort Bl[128][40];
  const int tid = threadIdx.x;
  const int lane = tid & 63;
  const int w8 = tid >> 6;
  const int wm = w8 >> 2;
  const int wn = w8 & 3;
  const int m16 = lane & 15;
  const int g4 = lane >> 4;
  const int m0 = blockIdx.y << 7;
  const int n0 = blockIdx.x << 7;

  const int srow = tid >> 2;
  const int sseg = (tid & 3) << 3;
  const ushort* ap = X + (size_t)(m0 + srow) * DMODEL + sseg;
  const ushort* wp = W + (size_t)(n0 + srow) * DMODEL + sseg;

  short8 pa = *(const short8*)(ap);
  short8 pb = *(const short8*)(wp);

  for (int kt = 0; kt < DMODEL / 32; ++kt) {
    __syncthreads();
    *(short8*)&Al[srow][sseg] = pa;
    *(short8*)&Bl[srow][sseg] = pb;
    __syncthreads();
    if (kt < DMODEL / 32 - 1) {  // prefetch next tile under the MFMAs
      pa = *(const short8*)(ap + (kt + 1) * 32);
      pb = *(const short8*)(wp + (kt + 1) * 32);
    }
    short8 af[4], bf[2];
#pragma unroll
    for (int mi = 0; mi < 4; ++mi)
      af[mi] = *(const short8*)&Al[(wm << 6) + (mi << 4) + m16][g4 << 3];
#pragma unroll
    for (int ni = 0; ni < 2; ++ni)
      bf[ni] = *(const short8*)&Bl[(wn << 5) + (ni << 4) + m16][g4 << 3];
#pragma unroll
    for (int mi = 0; mi < 4; ++mi)
#pragma unroll
      for (int ni = 0; ni < 2; ++ni)
        acc[mi][ni] = __builtin_amdgcn_mfma_f32_16x16x32_bf16(
            af[mi], bf[ni], acc[mi][ni], 0, 0, 0);
  }
}

// QKV: bf16 out, Q scaled by QSCALE. Grid: (8, M/128, 3)
__global__ __launch_bounds__(512) void qkv_mfma(
    const ushort* __restrict__ X,
    const ushort* __restrict__ wqb, const ushort* __restrict__ wkb,
    const ushort* __restrict__ wvb,
    const float* __restrict__ bq, const float* __restrict__ bk,
    const float* __restrict__ bv,
    ushort* __restrict__ Qb, ushort* __restrict__ Kb,
    ushort* __restrict__ Vb) {
  const int z = blockIdx.z;
  const ushort* W = (z == 0) ? wqb : (z == 1) ? wkb : wvb;
  const float* bias = (z == 0) ? bq : (z == 1) ? bk : bv;
  ushort* Y = (z == 0) ? Qb : (z == 1) ? Kb : Vb;
  const float oscale = (z == 0) ? QSCALE : 1.0f;

  f32x4 acc[4][2];
#pragma unroll
  for (int mi = 0; mi < 4; ++mi)
#pragma unroll
    for (int ni = 0; ni < 2; ++ni) acc[mi][ni] = (f32x4){0.f, 0.f, 0.f, 0.f};
  mfma_gemm_core(X, W, acc);

  const int tid = threadIdx.x;
  const int lane = tid & 63;
  const int w8 = tid >> 6;
  const int wm = w8 >> 2, wn = w8 & 3;
  const int m16 = lane & 15, g4 = lane >> 4;
  const int m0 = blockIdx.y << 7, n0 = blockIdx.x << 7;
#pragma unroll
  for (int ni = 0; ni < 2; ++ni) {
    const int col = n0 + (wn << 5) + (ni << 4) + m16;
    const float bv4 = bias[col];
#pragma unroll
    for (int mi = 0; mi < 4; ++mi)
#pragma unroll
      for (int r = 0; r < 4; ++r) {
        const int row = m0 + (wm << 6) + (mi << 4) + (g4 << 2) + r;
        Y[(size_t)row * DMODEL + col] = f2bf((acc[mi][ni][r] + bv4) * oscale);
      }
  }
}

// O-projection: bf16 in (Ab, wob), fp32 out + bias. Grid: (8, 32, 1)
__global__ __launch_bounds__(512) void oproj_mfma(
    const ushort* __restrict__ X, const ushort* __restrict__ wob,
    const float* __restrict__ bo, float* __restrict__ Y) {
  f32x4 acc[4][2];
#pragma unroll
  for (int mi = 0; mi < 4; ++mi)
#pragma unroll
    for (int ni = 0; ni < 2; ++ni) acc[mi][ni] = (f32x4){0.f, 0.f, 0.f, 0.f};
  mfma_gemm_core(X, wob, acc);

  const int tid = threadIdx.x;
  const int lane = tid & 63;
  const int w8 = tid >> 6;
  const int wm = w8 >> 2, wn = w8 & 3;
  const int m16 = lane & 15, g4 = lane >> 4;
  const int m0 = blockIdx.y << 7, n0 = blockIdx.x << 7;
#pragma unroll
  for (int ni = 0; ni < 2; ++ni) {
    const int col = n0 + (wn << 5) + (ni << 4) + m16;
    const float bv4 = bo[col];
#pragma unroll
    for (int mi = 0; mi < 4; ++mi)
#pragma unroll
      for (int r = 0; r < 4; ++r) {
        const int row = m0 + (wm << 6) + (mi << 4) + (g4 << 2) + r;
        Y[(size_t)row * DMODEL + col] = acc[mi][ni][r] + bv4;
      }
  }
}

// ---------------------------------------------------------------------------
// MFMA flash attention, round 16 = r15 split-K2 kernel with launch_bounds
// reverted to (512,4): r15's (512,8) forced the allocator to 32 VGPR ->
// massive scratch spills (FETCH 69->365MB, 2x slower). The bound only
// constrains the allocator; residency is resource-determined: at 52 VGPR
// (<=64 -> 8 waves/SIMD) and 36.9KB LDS (-> 4 blocks/CU) the HW can still
// co-schedule 32 waves/CU. Split = blockIdx.z&1 covers 1024 keys; emits
// per-split-normalized O + (m,l); merged by attn_merge.
// Grid: (SEQ/128, NH, BATCH*NSPLIT), 512 thr.
// ---------------------------------------------------------------------------
__global__ __launch_bounds__(512, 4) void attn_mfma(
    const ushort* __restrict__ Q, const ushort* __restrict__ K,
    const ushort* __restrict__ V, ushort* __restrict__ Opart,
    float2* __restrict__ ml) {
  __shared__ ushort Klds[2][64][72];
  __shared__ ushort Vlds[2][64][72];

  const int tid = threadIdx.x;
  const int lane = tid & 63;
  const int wv = tid >> 6;      // wave 0..7
  const int m16 = lane & 15;
  const int g4 = lane >> 4;     // 0..3
  const int b = blockIdx.z >> 1;
  const int split = blockIdx.z & 1;
  const int h = blockIdx.y;
  const int q0 = (blockIdx.x << 7) + (wv << 4);  // wave's 16-row q base

  const size_t base = ((size_t)b * SEQ) * DMODEL + h * DHEAD;  // elem offset
  const size_t elems = (size_t)BATCH * SEQ * DMODEL;

  // --- Q fragments (2 k-steps of 32 over DHEAD=64), rows = m16 ---
  short8 qf[2];
  {
    const ushort* qp = Q + base + (size_t)(q0 + m16) * DMODEL + (g4 << 3);
    qf[0] = *(const short8*)(qp);
    qf[1] = *(const short8*)(qp + 32);
  }

  f32x4 oacc[4];  // [dt]: col d = dt*16+m16, rows q = 4g4 + r
#pragma unroll
  for (int dt = 0; dt < 4; ++dt) oacc[dt] = (f32x4){0.f, 0.f, 0.f, 0.f};
  float mrow = -1e30f;  // running max for q = m16 (log2 domain)
  float lsum = 0.f;     // lane-partial denominator

  // staging map: 512 threads, key = tid>>3 (64), seg = tid&7; this split's
  // keys start at split*1024.
  const int skey = tid >> 3;
  const int sseg = tid & 7;
  const ushort* kgp =
      K + base + (size_t)(split * 1024 + skey) * DMODEL + (sseg << 3);
  const ushort* vgp =
      V + base + (size_t)(split * 1024 + skey) * DMODEL + (sseg << 3);
  const int vswz_key = skey ^ (sseg << 3);  // conflict-free u16 scatter

  // T14: tile-0 loads issued long before first use
  short8 kvec = *(const short8*)(kgp);
  short8 vvec = *(const short8*)(vgp);

  int p = 0;
  for (int kt = 0; kt < 1024 / 64; ++kt) {
    // stage tile kt into buffer p
    *(short8*)&Klds[p][skey][sseg << 3] = kvec;
#pragma unroll
    for (int i = 0; i < 8; ++i)
      Vlds[p][(sseg << 3) + i][vswz_key] = ((const ushort*)&vvec)[i];
    __syncthreads();  // the only barrier per tile (dbuf)
    // T14: issue next tile's global loads; latency hides under compute
    if (kt + 1 < 1024 / 64) {
      const size_t koff = (size_t)(kt + 1) * 64 * DMODEL;
      kvec = *(const short8*)(kgp + koff);
      vvec = *(const short8*)(vgp + koff);
    }

    // --- S^T = K * Q^T : s[kt2][r] = S[key=16*kt2+4*g4+r][q=m16] ---
    f32x4 s[4];
#pragma unroll
    for (int kt2 = 0; kt2 < 4; ++kt2) s[kt2] = (f32x4){0.f, 0.f, 0.f, 0.f};
    __builtin_amdgcn_s_setprio(1);
#pragma unroll
    for (int ks = 0; ks < 2; ++ks) {
#pragma unroll
      for (int kt2 = 0; kt2 < 4; ++kt2) {
        const short8 kf =
            *(const short8*)&Klds[p][(kt2 << 4) + m16][(ks << 5) + (g4 << 3)];
        s[kt2] =
            __builtin_amdgcn_mfma_f32_16x16x32_bf16(kf, qf[ks], s[kt2], 0, 0, 0);
      }
    }
    __builtin_amdgcn_s_setprio(0);

    // --- online softmax for q = m16 (exp2 domain) ---
    float t0 = fmaxf(fmaxf(s[0][0], s[0][1]), fmaxf(s[0][2], s[0][3]));
    float t1 = fmaxf(fmaxf(s[1][0], s[1][1]), fmaxf(s[1][2], s[1][3]));
    float t2 = fmaxf(fmaxf(s[2][0], s[2][1]), fmaxf(s[2][2], s[2][3]));
    float t3 = fmaxf(fmaxf(s[3][0], s[3][1]), fmaxf(s[3][2], s[3][3]));
    float tred = fmaxf(fmaxf(t0, t1), fmaxf(t2, t3));
    tred = fmaxf(tred, __shfl_xor(tred, 16));
    tred = fmaxf(tred, __shfl_xor(tred, 32));
    // T13 defer-max: only rescale when the max grew by more than 8
    if (!__all(tred <= mrow + 8.0f)) {
      const float mnew = fmaxf(mrow, tred);
      const float corr = exp2f(mrow - mnew);
      lsum *= corr;
      const float cb0 = __shfl(corr, (g4 << 2) + 0);
      const float cb1 = __shfl(corr, (g4 << 2) + 1);
      const float cb2 = __shfl(corr, (g4 << 2) + 2);
      const float cb3 = __shfl(corr, (g4 << 2) + 3);
#pragma unroll
      for (int dt = 0; dt < 4; ++dt) {
        oacc[dt][0] *= cb0; oacc[dt][1] *= cb1;
        oacc[dt][2] *= cb2; oacc[dt][3] *= cb3;
      }
      mrow = mnew;
    }
    float ps = 0.f;
#pragma unroll
    for (int kt2 = 0; kt2 < 4; ++kt2)
#pragma unroll
      for (int r = 0; r < 4; ++r) {
        const float pv = exp2f(s[kt2][r] - mrow);
        s[kt2][r] = pv;
        ps += pv;
      }
    lsum += ps;

    // --- P -> PV A-fragment, fully in registers (validated r12/r13) ---
    unsigned int W0 = cvtpk(s[0][0], s[0][1]);
    unsigned int W1 = cvtpk(s[0][2], s[0][3]);
    unsigned int W2 = cvtpk(s[1][0], s[1][1]);
    unsigned int W3 = cvtpk(s[1][2], s[1][3]);
    unsigned int W4 = cvtpk(s[2][0], s[2][1]);
    unsigned int W5 = cvtpk(s[2][2], s[2][3]);
    unsigned int W6 = cvtpk(s[3][0], s[3][1]);
    unsigned int W7 = cvtpk(s[3][2], s[3][3]);
    P32SWAP(W0, W2);
    P32SWAP(W1, W3);
    P32SWAP(W4, W6);
    P32SWAP(W5, W7);
    P16SWAP(W0, W2);
    P16SWAP(W1, W3);
    P16SWAP(W4, W6);
    P16SWAP(W5, W7);
    union { unsigned int u[4]; short8 v; } u0, u1;
    u0.u[0] = W0; u0.u[1] = W1; u0.u[2] = W2; u0.u[3] = W3;
    u1.u[0] = W4; u1.u[1] = W5; u1.u[2] = W6; u1.u[3] = W7;

    // --- O += P * V ---
    __builtin_amdgcn_s_setprio(1);
#pragma unroll
    for (int dt = 0; dt < 4; ++dt) {
      const int d = (dt << 4) + m16;
      const int swz = (d >> 3) << 3;
      const short8 vf0 = *(const short8*)&Vlds[p][d][(g4 << 3) ^ swz];
      oacc[dt] = __builtin_amdgcn_mfma_f32_16x16x32_bf16(
          u0.v, vf0, oacc[dt], 0, 0, 0);
      const short8 vf1 = *(const short8*)&Vlds[p][d][(32 + (g4 << 3)) ^ swz];
      oacc[dt] = __builtin_amdgcn_mfma_f32_16x16x32_bf16(
          u1.v, vf1, oacc[dt], 0, 0, 0);
    }
    __builtin_amdgcn_s_setprio(0);
    p ^= 1;
  }

  // --- epilogue: reduce lsum, normalize (per-split), store O + (m,l) ---
  lsum += __shfl_xor(lsum, 16);
  lsum += __shfl_xor(lsum, 32);
  // lanes 0..15 store (m, l) for q-rows q0..q0+15 of this (split,b,h)
  if (lane < 16) {
    ml[(((size_t)split * BATCH + b) * NH + h) * SEQ + q0 + lane] =
        make_float2(mrow, lsum);
  }
  const float inv = 1.0f / lsum;  // for q = m16, in all 4 g4 copies
  const float inv0 = __shfl(inv, (g4 << 2) + 0);
  const float inv1 = __shfl(inv, (g4 << 2) + 1);
  const float inv2 = __shfl(inv, (g4 << 2) + 2);
  const float inv3 = __shfl(inv, (g4 << 2) + 3);
  const float invr[4] = {inv0, inv1, inv2, inv3};
  ushort* obase = Opart + (size_t)split * elems;
#pragma unroll
  for (int r = 0; r < 4; ++r) {
    const size_t row = (size_t)(q0 + (g4 << 2) + r);
    ushort* op = obase + ((size_t)b * SEQ + row) * DMODEL + h * DHEAD + m16;
#pragma unroll
    for (int dt = 0; dt < 4; ++dt) op[dt << 4] = f2bf(oacc[dt][r] * invr[r]);
  }
}

// ---------------------------------------------------------------------------
// Merge the two per-split-normalized partials:
//   w_i = l_i * 2^(m_i - m) / sum,  O = w0*O0 + w1*O1   (exp2 domain)
// Writes IN PLACE over split-0's buffer (thread-local idx-for-idx: race-free,
// and attn rewrites the buffer each call -> replay-deterministic).
// ---------------------------------------------------------------------------
__global__ __launch_bounds__(256) void attn_merge(
    ushort* __restrict__ Opart, const float2* __restrict__ ml) {
  const size_t elems = (size_t)BATCH * SEQ * DMODEL;
  const size_t e0 = ((size_t)blockIdx.x * 256 + threadIdx.x) * 8;
  if (e0 >= elems) return;
  const int b = (int)(e0 / ((size_t)SEQ * DMODEL));
  const size_t rem = e0 % ((size_t)SEQ * DMODEL);
  const int s = (int)(rem / DMODEL);
  const int d = (int)(rem % DMODEL);
  const int h = d >> 6;

  const float2 ml0 = ml[(((size_t)0 * BATCH + b) * NH + h) * SEQ + s];
  const float2 ml1 = ml[(((size_t)1 * BATCH + b) * NH + h) * SEQ + s];
  const float m = fmaxf(ml0.x, ml1.x);
  const float a0 = ml0.y * exp2f(ml0.x - m);
  const float a1 = ml1.y * exp2f(ml1.x - m);
  const float inv = 1.0f / (a0 + a1);
  const float w0 = a0 * inv;
  const float w1 = a1 * inv;

  const short8 o0 = *(const short8*)(Opart + e0);
  const short8 o1 = *(const short8*)(Opart + elems + e0);
  short8 o;
#pragma unroll
  for (int j = 0; j < 8; ++j) {
    const float v =
        w0 * bf2f((ushort)o0[j]) + w1 * bf2f((ushort)o1[j]);
    o[j] = (short)f2bf(v);
  }
  *(short8*)(Opart + e0) = o;
}

// ---------------------------------------------------------------------------
extern "C" void kernel_launch(void* const* d_in, const int* in_sizes, int n_in,
                              void* d_out, int out_size, void* d_ws,
                              size_t ws_size, hipStream_t stream) {
  const float* hs = (const float*)d_in[0];
  const float* wq = (const float*)d_in[1];
  const float* bq = (const float*)d_in[2];
  const float* wk = (const float*)d_in[3];
  const float* bk = (const float*)d_in[4];
  const float* wv = (const float*)d_in[5];
  const float* bv = (const float*)d_in[6];
  const float* wo = (const float*)d_in[7];
  const float* bo = (const float*)d_in[8];
  float* out = (float*)d_out;

  // ws layout (ushort elems): hsb 4M | wqb/wkb/wvb/wob 1M each | Qb/Kb/Vb 4M
  // | Opart 8M (2 splits; split 0 doubles as merged Ab) | ml 1MB
  // total = 28M ushorts (56 MiB) + 1 MiB = 57 MiB (r3 proved >= 64 MiB ws)
  const size_t elems = (size_t)BATCH * SEQ * DMODEL;  // 4M
  const size_t welems = (size_t)DMODEL * DMODEL;      // 1M
  ushort* hsb = (ushort*)d_ws;
  ushort* wqb = hsb + elems;
  ushort* wkb = wqb + welems;
  ushort* wvb = wkb + welems;
  ushort* wob = wvb + welems;
  ushort* Qb = wob + welems;
  ushort* Kb = Qb + elems;
  ushort* Vb = Kb + elems;
  ushort* Opart = Vb + elems;                      // 2 * elems ushorts
  float2* ml = (float2*)(Opart + NSPLIT * elems);  // NSPLIT*B*NH*SEQ float2

  cast_all<<<dim3((int)(elems / (256 * 8)), 5, 1), 256, 0, stream>>>(
      hs, wq, wk, wv, wo, hsb, wqb, wkb, wvb, wob);
  qkv_mfma<<<dim3(DMODEL / 128, (BATCH * SEQ) / 128, 3), 512, 0, stream>>>(
      hsb, wqb, wkb, wvb, bq, bk, bv, Qb, Kb, Vb);
  attn_mfma<<<dim3(SEQ / 128, NH, BATCH * NSPLIT), 512, 0, stream>>>(
      Qb, Kb, Vb, Opart, ml);
  attn_merge<<<dim3((int)(elems / (256 * 8)), 1, 1), 256, 0, stream>>>(
      Opart, ml);
  oproj_mfma<<<dim3(DMODEL / 128, (BATCH * SEQ) / 128, 1), 512, 0, stream>>>(
      Opart, wob, bo, out);
}

// Round 17
// 138.307 us; speedup vs baseline: 1.5427x; 1.0575x over previous
//
#include <hip/hip_runtime.h>
#include <math.h>

#define BATCH  2
#define SEQ    2048
#define NH     16
#define DMODEL 1024
#define DHEAD  64

typedef short short8 __attribute__((ext_vector_type(8)));
typedef float f32x4 __attribute__((ext_vector_type(4)));

// Q pre-scale: 1/sqrt(64) * log2(e)  -> softmax via exp2
#define QSCALE 0.18033688011112042f

__device__ __forceinline__ ushort f2bf(float f) {
  // round-to-nearest-even f32 -> bf16 (finite inputs only)
  unsigned int u = __builtin_bit_cast(unsigned int, f);
  u = (u + 0x7FFFu + ((u >> 16) & 1u)) >> 16;
  return (ushort)u;
}

// pack two f32 -> one u32 of two bf16 (RNE), single HW instruction
__device__ __forceinline__ unsigned int cvtpk(float lo, float hi) {
  unsigned int r;
  asm("v_cvt_pk_bf16_f32 %0, %1, %2" : "=v"(r) : "v"(lo), "v"(hi));
  return r;
}

// gfx950 cross-lane swaps (VALU pipe, 1 instr).
// CORRECTNESS (r11 post-mortem): operands MUST be distinct SSA values —
// copies of one value get register-coalesced and the instruction
// self-swaps (data loss). Butterfly operands are distinct cvt_pk outputs.
// Reductions over copies of one value use __shfl_xor instead.
#define P32SWAP(a, b) \
  asm("v_permlane32_swap_b32 %0, %1" : "+v"(a), "+v"(b))
#define P16SWAP(a, b) \
  asm("v_permlane16_swap_b32 %0, %1" : "+v"(a), "+v"(b))

// ---------------------------------------------------------------------------
// Cast fp32 -> bf16: z=0 hs (4M elems), z=1..4 wq/wk/wv/wo (1M each).
// (Separate pass proven faster than fused-into-GEMM staging — r14 A/B.)
// ---------------------------------------------------------------------------
__global__ __launch_bounds__(256) void cast_all(
    const float* __restrict__ hs, const float* __restrict__ wq,
    const float* __restrict__ wk, const float* __restrict__ wv,
    const float* __restrict__ wo,
    ushort* __restrict__ hsb, ushort* __restrict__ wqb,
    ushort* __restrict__ wkb, ushort* __restrict__ wvb,
    ushort* __restrict__ wob) {
  const int z = blockIdx.y;
  const float* s = (z == 0) ? hs : (z == 1) ? wq : (z == 2) ? wk
                   : (z == 3) ? wv : wo;
  ushort* d = (z == 0) ? hsb : (z == 1) ? wqb : (z == 2) ? wkb
              : (z == 3) ? wvb : wob;
  const int n = (z == 0) ? BATCH * SEQ * DMODEL : DMODEL * DMODEL;
  const int i = (blockIdx.x * 256 + threadIdx.x) * 8;
  if (i < n) {
    const float4 a = *(const float4*)(s + i);
    const float4 b = *(const float4*)(s + i + 4);
    short8 o;
    o[0] = (short)f2bf(a.x); o[1] = (short)f2bf(a.y);
    o[2] = (short)f2bf(a.z); o[3] = (short)f2bf(a.w);
    o[4] = (short)f2bf(b.x); o[5] = (short)f2bf(b.y);
    o[6] = (short)f2bf(b.z); o[7] = (short)f2bf(b.w);
    *(short8*)(d + i) = o;
  }
}

// ---------------------------------------------------------------------------
// bf16 MFMA GEMM tile body: 128x128 tile, BK=32, 512 thr = 8 waves (2m x 4n),
// wave tile 64x32 = 4x2 frags of 16x16x32.  Validated rounds 5-16.
// ---------------------------------------------------------------------------
__device__ __forceinline__ void mfma_gemm_core(
    const ushort* __restrict__ X, const ushort* __restrict__ W,
    f32x4 (&acc)[4][2]) {
  __shared__ ushort Al[128][40];
  __shared__ ushort Bl[128][40];
  const int tid = threadIdx.x;
  const int lane = tid & 63;
  const int w8 = tid >> 6;
  const int wm = w8 >> 2;
  const int wn = w8 & 3;
  const int m16 = lane & 15;
  const int g4 = lane >> 4;
  const int m0 = blockIdx.y << 7;
  const int n0 = blockIdx.x << 7;

  const int srow = tid >> 2;
  const int sseg = (tid & 3) << 3;
  const ushort* ap = X + (size_t)(m0 + srow) * DMODEL + sseg;
  const ushort* wp = W + (size_t)(n0 + srow) * DMODEL + sseg;

  short8 pa = *(const short8*)(ap);
  short8 pb = *(const short8*)(wp);

  for (int kt = 0; kt < DMODEL / 32; ++kt) {
    __syncthreads();
    *(short8*)&Al[srow][sseg] = pa;
    *(short8*)&Bl[srow][sseg] = pb;
    __syncthreads();
    if (kt < DMODEL / 32 - 1) {  // prefetch next tile under the MFMAs
      pa = *(const short8*)(ap + (kt + 1) * 32);
      pb = *(const short8*)(wp + (kt + 1) * 32);
    }
    short8 af[4], bf[2];
#pragma unroll
    for (int mi = 0; mi < 4; ++mi)
      af[mi] = *(const short8*)&Al[(wm << 6) + (mi << 4) + m16][g4 << 3];
#pragma unroll
    for (int ni = 0; ni < 2; ++ni)
      bf[ni] = *(const short8*)&Bl[(wn << 5) + (ni << 4) + m16][g4 << 3];
#pragma unroll
    for (int mi = 0; mi < 4; ++mi)
#pragma unroll
      for (int ni = 0; ni < 2; ++ni)
        acc[mi][ni] = __builtin_amdgcn_mfma_f32_16x16x32_bf16(
            af[mi], bf[ni], acc[mi][ni], 0, 0, 0);
  }
}

// QKV: bf16 out, Q scaled by QSCALE. Grid: (8, M/128, 3)
__global__ __launch_bounds__(512) void qkv_mfma(
    const ushort* __restrict__ X,
    const ushort* __restrict__ wqb, const ushort* __restrict__ wkb,
    const ushort* __restrict__ wvb,
    const float* __restrict__ bq, const float* __restrict__ bk,
    const float* __restrict__ bv,
    ushort* __restrict__ Qb, ushort* __restrict__ Kb,
    ushort* __restrict__ Vb) {
  const int z = blockIdx.z;
  const ushort* W = (z == 0) ? wqb : (z == 1) ? wkb : wvb;
  const float* bias = (z == 0) ? bq : (z == 1) ? bk : bv;
  ushort* Y = (z == 0) ? Qb : (z == 1) ? Kb : Vb;
  const float oscale = (z == 0) ? QSCALE : 1.0f;

  f32x4 acc[4][2];
#pragma unroll
  for (int mi = 0; mi < 4; ++mi)
#pragma unroll
    for (int ni = 0; ni < 2; ++ni) acc[mi][ni] = (f32x4){0.f, 0.f, 0.f, 0.f};
  mfma_gemm_core(X, W, acc);

  const int tid = threadIdx.x;
  const int lane = tid & 63;
  const int w8 = tid >> 6;
  const int wm = w8 >> 2, wn = w8 & 3;
  const int m16 = lane & 15, g4 = lane >> 4;
  const int m0 = blockIdx.y << 7, n0 = blockIdx.x << 7;
#pragma unroll
  for (int ni = 0; ni < 2; ++ni) {
    const int col = n0 + (wn << 5) + (ni << 4) + m16;
    const float bv4 = bias[col];
#pragma unroll
    for (int mi = 0; mi < 4; ++mi)
#pragma unroll
      for (int r = 0; r < 4; ++r) {
        const int row = m0 + (wm << 6) + (mi << 4) + (g4 << 2) + r;
        Y[(size_t)row * DMODEL + col] = f2bf((acc[mi][ni][r] + bv4) * oscale);
      }
  }
}

// O-projection: bf16 in (Ab, wob), fp32 out + bias. Grid: (8, 32, 1)
__global__ __launch_bounds__(512) void oproj_mfma(
    const ushort* __restrict__ X, const ushort* __restrict__ wob,
    const float* __restrict__ bo, float* __restrict__ Y) {
  f32x4 acc[4][2];
#pragma unroll
  for (int mi = 0; mi < 4; ++mi)
#pragma unroll
    for (int ni = 0; ni < 2; ++ni) acc[mi][ni] = (f32x4){0.f, 0.f, 0.f, 0.f};
  mfma_gemm_core(X, wob, acc);

  const int tid = threadIdx.x;
  const int lane = tid & 63;
  const int w8 = tid >> 6;
  const int wm = w8 >> 2, wn = w8 & 3;
  const int m16 = lane & 15, g4 = lane >> 4;
  const int m0 = blockIdx.y << 7, n0 = blockIdx.x << 7;
#pragma unroll
  for (int ni = 0; ni < 2; ++ni) {
    const int col = n0 + (wn << 5) + (ni << 4) + m16;
    const float bv4 = bo[col];
#pragma unroll
    for (int mi = 0; mi < 4; ++mi)
#pragma unroll
      for (int r = 0; r < 4; ++r) {
        const int row = m0 + (wm << 6) + (mi << 4) + (g4 << 2) + r;
        Y[(size_t)row * DMODEL + col] = acc[mi][ni][r] + bv4;
      }
  }
}

// ---------------------------------------------------------------------------
// MFMA flash attention (r13 configuration — session best, 79 us):
// 512 thr = 8 waves x 16 q-rows, 4 waves/SIMD; permlane reg-P butterfly,
// no P-LDS; swapped QK^T, defer-max THR=8, single-barrier K/V dbuf, T14
// prefetch, setprio, V XOR-scatter staging.
// r13<->r16 A/B established this kernel is VALU-issue-bound (softmax's
// ~3-4 ops/score), not latency-bound: split-K occupancy boost was a null.
// Grid: (SEQ/128, NH, BATCH) = 512 blocks, 512 thr.
// ---------------------------------------------------------------------------
__global__ __launch_bounds__(512, 4) void attn_mfma(
    const ushort* __restrict__ Q, const ushort* __restrict__ K,
    const ushort* __restrict__ V, ushort* __restrict__ O) {
  __shared__ ushort Klds[2][64][72];
  __shared__ ushort Vlds[2][64][72];

  const int tid = threadIdx.x;
  const int lane = tid & 63;
  const int wv = tid >> 6;      // wave 0..7
  const int m16 = lane & 15;
  const int g4 = lane >> 4;     // 0..3
  const int b = blockIdx.z;
  const int h = blockIdx.y;
  const int q0 = (blockIdx.x << 7) + (wv << 4);  // wave's 16-row q base

  const size_t base = ((size_t)b * SEQ) * DMODEL + h * DHEAD;  // elem offset

  // --- Q fragments (2 k-steps of 32 over DHEAD=64), rows = m16 ---
  short8 qf[2];
  {
    const ushort* qp = Q + base + (size_t)(q0 + m16) * DMODEL + (g4 << 3);
    qf[0] = *(const short8*)(qp);
    qf[1] = *(const short8*)(qp + 32);
  }

  f32x4 oacc[4];  // [dt]: col d = dt*16+m16, rows q = 4g4 + r
#pragma unroll
  for (int dt = 0; dt < 4; ++dt) oacc[dt] = (f32x4){0.f, 0.f, 0.f, 0.f};
  float mrow = -1e30f;  // running max for q = m16 (log2 domain)
  float lsum = 0.f;     // lane-partial denominator

  // staging map: 512 threads, key = tid>>3 (64), seg = tid&7
  const int skey = tid >> 3;
  const int sseg = tid & 7;
  const ushort* kgp = K + base + (size_t)skey * DMODEL + (sseg << 3);
  const ushort* vgp = V + base + (size_t)skey * DMODEL + (sseg << 3);
  const int vswz_key = skey ^ (sseg << 3);  // conflict-free u16 scatter

  // T14: tile-0 loads issued long before first use
  short8 kvec = *(const short8*)(kgp);
  short8 vvec = *(const short8*)(vgp);

  int p = 0;
  for (int kt = 0; kt < SEQ / 64; ++kt) {
    // stage tile kt into buffer p
    *(short8*)&Klds[p][skey][sseg << 3] = kvec;
#pragma unroll
    for (int i = 0; i < 8; ++i)
      Vlds[p][(sseg << 3) + i][vswz_key] = ((const ushort*)&vvec)[i];
    __syncthreads();  // the only barrier per tile (dbuf)
    // T14: issue next tile's global loads; latency hides under compute
    if (kt + 1 < SEQ / 64) {
      const size_t koff = (size_t)(kt + 1) * 64 * DMODEL;
      kvec = *(const short8*)(kgp + koff);
      vvec = *(const short8*)(vgp + koff);
    }

    // --- S^T = K * Q^T : s[kt2][r] = S[key=16*kt2+4*g4+r][q=m16] ---
    f32x4 s[4];
#pragma unroll
    for (int kt2 = 0; kt2 < 4; ++kt2) s[kt2] = (f32x4){0.f, 0.f, 0.f, 0.f};
    __builtin_amdgcn_s_setprio(1);
#pragma unroll
    for (int ks = 0; ks < 2; ++ks) {
#pragma unroll
      for (int kt2 = 0; kt2 < 4; ++kt2) {
        const short8 kf =
            *(const short8*)&Klds[p][(kt2 << 4) + m16][(ks << 5) + (g4 << 3)];
        s[kt2] =
            __builtin_amdgcn_mfma_f32_16x16x32_bf16(kf, qf[ks], s[kt2], 0, 0, 0);
      }
    }
    __builtin_amdgcn_s_setprio(0);

    // --- online softmax for q = m16 (exp2 domain) ---
    float t0 = fmaxf(fmaxf(s[0][0], s[0][1]), fmaxf(s[0][2], s[0][3]));
    float t1 = fmaxf(fmaxf(s[1][0], s[1][1]), fmaxf(s[1][2], s[1][3]));
    float t2 = fmaxf(fmaxf(s[2][0], s[2][1]), fmaxf(s[2][2], s[2][3]));
    float t3 = fmaxf(fmaxf(s[3][0], s[3][1]), fmaxf(s[3][2], s[3][3]));
    float tred = fmaxf(fmaxf(t0, t1), fmaxf(t2, t3));
    tred = fmaxf(tred, __shfl_xor(tred, 16));
    tred = fmaxf(tred, __shfl_xor(tred, 32));
    // T13 defer-max: only rescale when the max grew by more than 8
    if (!__all(tred <= mrow + 8.0f)) {
      const float mnew = fmaxf(mrow, tred);
      const float corr = exp2f(mrow - mnew);
      lsum *= corr;
      const float cb0 = __shfl(corr, (g4 << 2) + 0);
      const float cb1 = __shfl(corr, (g4 << 2) + 1);
      const float cb2 = __shfl(corr, (g4 << 2) + 2);
      const float cb3 = __shfl(corr, (g4 << 2) + 3);
#pragma unroll
      for (int dt = 0; dt < 4; ++dt) {
        oacc[dt][0] *= cb0; oacc[dt][1] *= cb1;
        oacc[dt][2] *= cb2; oacc[dt][3] *= cb3;
      }
      mrow = mnew;
    }
    float ps = 0.f;
#pragma unroll
    for (int kt2 = 0; kt2 < 4; ++kt2)
#pragma unroll
      for (int r = 0; r < 4; ++r) {
        const float pv = exp2f(s[kt2][r] - mrow);
        s[kt2][r] = pv;
        ps += pv;
      }
    lsum += ps;

    // --- P -> PV A-fragment, fully in registers (validated r12/r13) ---
    // pack: W[2*kt2+h] = bf16 pair = key-pair KP = 8*kt2 + 2*g4 + h
    unsigned int W0 = cvtpk(s[0][0], s[0][1]);
    unsigned int W1 = cvtpk(s[0][2], s[0][3]);
    unsigned int W2 = cvtpk(s[1][0], s[1][1]);
    unsigned int W3 = cvtpk(s[1][2], s[1][3]);
    unsigned int W4 = cvtpk(s[2][0], s[2][1]);
    unsigned int W5 = cvtpk(s[2][2], s[2][3]);
    unsigned int W6 = cvtpk(s[3][0], s[3][1]);
    unsigned int W7 = cvtpk(s[3][2], s[3][3]);
    // stage A: swap reg-bit(k3) <-> lane-bit5
    P32SWAP(W0, W2);
    P32SWAP(W1, W3);
    P32SWAP(W4, W6);
    P32SWAP(W5, W7);
    // stage B: swap reg-bit(k2) <-> lane-bit4
    P16SWAP(W0, W2);
    P16SWAP(W1, W3);
    P16SWAP(W4, W6);
    P16SWAP(W5, W7);
    union { unsigned int u[4]; short8 v; } u0, u1;
    u0.u[0] = W0; u0.u[1] = W1; u0.u[2] = W2; u0.u[3] = W3;
    u1.u[0] = W4; u1.u[1] = W5; u1.u[2] = W6; u1.u[3] = W7;

    // --- O += P * V ---
    __builtin_amdgcn_s_setprio(1);
#pragma unroll
    for (int dt = 0; dt < 4; ++dt) {
      const int d = (dt << 4) + m16;
      const int swz = (d >> 3) << 3;
      const short8 vf0 = *(const short8*)&Vlds[p][d][(g4 << 3) ^ swz];
      oacc[dt] = __builtin_amdgcn_mfma_f32_16x16x32_bf16(
          u0.v, vf0, oacc[dt], 0, 0, 0);
      const short8 vf1 = *(const short8*)&Vlds[p][d][(32 + (g4 << 3)) ^ swz];
      oacc[dt] = __builtin_amdgcn_mfma_f32_16x16x32_bf16(
          u1.v, vf1, oacc[dt], 0, 0, 0);
    }
    __builtin_amdgcn_s_setprio(0);
    p ^= 1;
  }

  // --- epilogue: reduce lsum across the 4 q-column copies, normalize ---
  lsum += __shfl_xor(lsum, 16);
  lsum += __shfl_xor(lsum, 32);
  const float inv = 1.0f / lsum;  // for q = m16, in all 4 g4 copies
  const float inv0 = __shfl(inv, (g4 << 2) + 0);
  const float inv1 = __shfl(inv, (g4 << 2) + 1);
  const float inv2 = __shfl(inv, (g4 << 2) + 2);
  const float inv3 = __shfl(inv, (g4 << 2) + 3);
  const float invr[4] = {inv0, inv1, inv2, inv3};
#pragma unroll
  for (int r = 0; r < 4; ++r) {
    const size_t row = (size_t)(q0 + (g4 << 2) + r);
    ushort* op = O + ((size_t)b * SEQ + row) * DMODEL + h * DHEAD + m16;
#pragma unroll
    for (int dt = 0; dt < 4; ++dt) op[dt << 4] = f2bf(oacc[dt][r] * invr[r]);
  }
}

// ---------------------------------------------------------------------------
extern "C" void kernel_launch(void* const* d_in, const int* in_sizes, int n_in,
                              void* d_out, int out_size, void* d_ws,
                              size_t ws_size, hipStream_t stream) {
  const float* hs = (const float*)d_in[0];
  const float* wq = (const float*)d_in[1];
  const float* bq = (const float*)d_in[2];
  const float* wk = (const float*)d_in[3];
  const float* bk = (const float*)d_in[4];
  const float* wv = (const float*)d_in[5];
  const float* bv = (const float*)d_in[6];
  const float* wo = (const float*)d_in[7];
  const float* bo = (const float*)d_in[8];
  float* out = (float*)d_out;

  // ws layout (ushort elems): hsb 4M | wqb/wkb/wvb/wob 1M each | Qb/Kb/Vb 4M
  // | Ab 4M  -> 24M ushorts = 48 MiB
  const size_t elems = (size_t)BATCH * SEQ * DMODEL;  // 4M
  const size_t welems = (size_t)DMODEL * DMODEL;      // 1M
  ushort* hsb = (ushort*)d_ws;
  ushort* wqb = hsb + elems;
  ushort* wkb = wqb + welems;
  ushort* wvb = wkb + welems;
  ushort* wob = wvb + welems;
  ushort* Qb = wob + welems;
  ushort* Kb = Qb + elems;
  ushort* Vb = Kb + elems;
  ushort* Ab = Vb + elems;

  cast_all<<<dim3((int)(elems / (256 * 8)), 5, 1), 256, 0, stream>>>(
      hs, wq, wk, wv, wo, hsb, wqb, wkb, wvb, wob);
  qkv_mfma<<<dim3(DMODEL / 128, (BATCH * SEQ) / 128, 3), 512, 0, stream>>>(
      hsb, wqb, wkb, wvb, bq, bk, bv, Qb, Kb, Vb);
  attn_mfma<<<dim3(SEQ / 128, NH, BATCH), 512, 0, stream>>>(Qb, Kb, Vb, Ab);
  oproj_mfma<<<dim3(DMODEL / 128, (BATCH * SEQ) / 128, 1), 512, 0, stream>>>(
      Ab, wob, bo, out);
}

// Round 18
// 127.826 us; speedup vs baseline: 1.6692x; 1.0820x over previous
//
#include <hip/hip_runtime.h>
#include <math.h>

#define BATCH  2
#define SEQ    2048
#define NH     16
#define DMODEL 1024
#define DHEAD  64

typedef short short8 __attribute__((ext_vector_type(8)));
typedef float f32x4 __attribute__((ext_vector_type(4)));

// Q pre-scale: 1/sqrt(64) * log2(e)  -> softmax via exp2
#define QSCALE 0.18033688011112042f

__device__ __forceinline__ ushort f2bf(float f) {
  // round-to-nearest-even f32 -> bf16 (finite inputs only)
  unsigned int u = __builtin_bit_cast(unsigned int, f);
  u = (u + 0x7FFFu + ((u >> 16) & 1u)) >> 16;
  return (ushort)u;
}

__device__ __forceinline__ float bf2f(ushort u) {
  const unsigned int v = ((unsigned int)u) << 16;
  return __builtin_bit_cast(float, v);
}

// Raw HW 2^x (v_exp_f32, ~1 ULP). exp2f() without -ffast-math goes through
// __ocml_exp2_f32 (guarded multi-instruction expansion) — at 16 calls/tile
// in the hot loop that was the prime suspect for the 6x VALU-count gap.
// Arguments here are bounded (|s-m| <~ 30), so the raw op is safe.
#if __has_builtin(__builtin_amdgcn_exp2f)
__device__ __forceinline__ float exp2_hw(float x) {
  return __builtin_amdgcn_exp2f(x);
}
#else
__device__ __forceinline__ float exp2_hw(float x) {
  float r;
  asm("v_exp_f32 %0, %1" : "=v"(r) : "v"(x));  // register-only, no mem hazard
  return r;
}
#endif

// pack two f32 -> one u32 of two bf16 (RNE), single HW instruction
__device__ __forceinline__ unsigned int cvtpk(float lo, float hi) {
  unsigned int r;
  asm("v_cvt_pk_bf16_f32 %0, %1, %2" : "=v"(r) : "v"(lo), "v"(hi));
  return r;
}

// gfx950 cross-lane swaps (VALU pipe, 1 instr).
// CORRECTNESS (r11 post-mortem): operands MUST be distinct SSA values —
// copies of one value get register-coalesced and the instruction
// self-swaps (data loss). Butterfly operands are distinct cvt_pk outputs.
// Reductions over copies of one value use __shfl_xor instead.
#define P32SWAP(a, b) \
  asm("v_permlane32_swap_b32 %0, %1" : "+v"(a), "+v"(b))
#define P16SWAP(a, b) \
  asm("v_permlane16_swap_b32 %0, %1" : "+v"(a), "+v"(b))

// ---------------------------------------------------------------------------
// Cast fp32 -> bf16: z=0 hs (4M elems), z=1..4 wq/wk/wv/wo (1M each).
// (Separate pass proven faster than fused-into-GEMM staging — r14 A/B.)
// ---------------------------------------------------------------------------
__global__ __launch_bounds__(256) void cast_all(
    const float* __restrict__ hs, const float* __restrict__ wq,
    const float* __restrict__ wk, const float* __restrict__ wv,
    const float* __restrict__ wo,
    ushort* __restrict__ hsb, ushort* __restrict__ wqb,
    ushort* __restrict__ wkb, ushort* __restrict__ wvb,
    ushort* __restrict__ wob) {
  const int z = blockIdx.y;
  const float* s = (z == 0) ? hs : (z == 1) ? wq : (z == 2) ? wk
                   : (z == 3) ? wv : wo;
  ushort* d = (z == 0) ? hsb : (z == 1) ? wqb : (z == 2) ? wkb
              : (z == 3) ? wvb : wob;
  const int n = (z == 0) ? BATCH * SEQ * DMODEL : DMODEL * DMODEL;
  const int i = (blockIdx.x * 256 + threadIdx.x) * 8;
  if (i < n) {
    const float4 a = *(const float4*)(s + i);
    const float4 b = *(const float4*)(s + i + 4);
    short8 o;
    o[0] = (short)f2bf(a.x); o[1] = (short)f2bf(a.y);
    o[2] = (short)f2bf(a.z); o[3] = (short)f2bf(a.w);
    o[4] = (short)f2bf(b.x); o[5] = (short)f2bf(b.y);
    o[6] = (short)f2bf(b.z); o[7] = (short)f2bf(b.w);
    *(short8*)(d + i) = o;
  }
}

// ---------------------------------------------------------------------------
// bf16 MFMA GEMM tile body: 128x128 tile, BK=32, 512 thr = 8 waves (2m x 4n),
// wave tile 64x32 = 4x2 frags of 16x16x32.  Validated rounds 5-17.
// ---------------------------------------------------------------------------
__device__ __forceinline__ void mfma_gemm_core(
    const ushort* __restrict__ X, const ushort* __restrict__ W,
    f32x4 (&acc)[4][2]) {
  __shared__ ushort Al[128][40];
  __shared__ ushort Bl[128][40];
  const int tid = threadIdx.x;
  const int lane = tid & 63;
  const int w8 = tid >> 6;
  const int wm = w8 >> 2;
  const int wn = w8 & 3;
  const int m16 = lane & 15;
  const int g4 = lane >> 4;
  const int m0 = blockIdx.y << 7;
  const int n0 = blockIdx.x << 7;

  const int srow = tid >> 2;
  const int sseg = (tid & 3) << 3;
  const ushort* ap = X + (size_t)(m0 + srow) * DMODEL + sseg;
  const ushort* wp = W + (size_t)(n0 + srow) * DMODEL + sseg;

  short8 pa = *(const short8*)(ap);
  short8 pb = *(const short8*)(wp);

  for (int kt = 0; kt < DMODEL / 32; ++kt) {
    __syncthreads();
    *(short8*)&Al[srow][sseg] = pa;
    *(short8*)&Bl[srow][sseg] = pb;
    __syncthreads();
    if (kt < DMODEL / 32 - 1) {  // prefetch next tile under the MFMAs
      pa = *(const short8*)(ap + (kt + 1) * 32);
      pb = *(const short8*)(wp + (kt + 1) * 32);
    }
    short8 af[4], bf[2];
#pragma unroll
    for (int mi = 0; mi < 4; ++mi)
      af[mi] = *(const short8*)&Al[(wm << 6) + (mi << 4) + m16][g4 << 3];
#pragma unroll
    for (int ni = 0; ni < 2; ++ni)
      bf[ni] = *(const short8*)&Bl[(wn << 5) + (ni << 4) + m16][g4 << 3];
#pragma unroll
    for (int mi = 0; mi < 4; ++mi)
#pragma unroll
      for (int ni = 0; ni < 2; ++ni)
        acc[mi][ni] = __builtin_amdgcn_mfma_f32_16x16x32_bf16(
            af[mi], bf[ni], acc[mi][ni], 0, 0, 0);
  }
}

// QKV: bf16 out, Q scaled by QSCALE. Grid: (8, M/128, 3)
__global__ __launch_bounds__(512) void qkv_mfma(
    const ushort* __restrict__ X,
    const ushort* __restrict__ wqb, const ushort* __restrict__ wkb,
    const ushort* __restrict__ wvb,
    const float* __restrict__ bq, const float* __restrict__ bk,
    const float* __restrict__ bv,
    ushort* __restrict__ Qb, ushort* __restrict__ Kb,
    ushort* __restrict__ Vb) {
  const int z = blockIdx.z;
  const ushort* W = (z == 0) ? wqb : (z == 1) ? wkb : wvb;
  const float* bias = (z == 0) ? bq : (z == 1) ? bk : bv;
  ushort* Y = (z == 0) ? Qb : (z == 1) ? Kb : Vb;
  const float oscale = (z == 0) ? QSCALE : 1.0f;

  f32x4 acc[4][2];
#pragma unroll
  for (int mi = 0; mi < 4; ++mi)
#pragma unroll
    for (int ni = 0; ni < 2; ++ni) acc[mi][ni] = (f32x4){0.f, 0.f, 0.f, 0.f};
  mfma_gemm_core(X, W, acc);

  const int tid = threadIdx.x;
  const int lane = tid & 63;
  const int w8 = tid >> 6;
  const int wm = w8 >> 2, wn = w8 & 3;
  const int m16 = lane & 15, g4 = lane >> 4;
  const int m0 = blockIdx.y << 7, n0 = blockIdx.x << 7;
#pragma unroll
  for (int ni = 0; ni < 2; ++ni) {
    const int col = n0 + (wn << 5) + (ni << 4) + m16;
    const float bv4 = bias[col];
#pragma unroll
    for (int mi = 0; mi < 4; ++mi)
#pragma unroll
      for (int r = 0; r < 4; ++r) {
        const int row = m0 + (wm << 6) + (mi << 4) + (g4 << 2) + r;
        Y[(size_t)row * DMODEL + col] = f2bf((acc[mi][ni][r] + bv4) * oscale);
      }
  }
}

// O-projection: bf16 in (Ab, wob), fp32 out + bias. Grid: (8, 32, 1)
__global__ __launch_bounds__(512) void oproj_mfma(
    const ushort* __restrict__ X, const ushort* __restrict__ wob,
    const float* __restrict__ bo, float* __restrict__ Y) {
  f32x4 acc[4][2];
#pragma unroll
  for (int mi = 0; mi < 4; ++mi)
#pragma unroll
    for (int ni = 0; ni < 2; ++ni) acc[mi][ni] = (f32x4){0.f, 0.f, 0.f, 0.f};
  mfma_gemm_core(X, wob, acc);

  const int tid = threadIdx.x;
  const int lane = tid & 63;
  const int w8 = tid >> 6;
  const int wm = w8 >> 2, wn = w8 & 3;
  const int m16 = lane & 15, g4 = lane >> 4;
  const int m0 = blockIdx.y << 7, n0 = blockIdx.x << 7;
#pragma unroll
  for (int ni = 0; ni < 2; ++ni) {
    const int col = n0 + (wn << 5) + (ni << 4) + m16;
    const float bv4 = bo[col];
#pragma unroll
    for (int mi = 0; mi < 4; ++mi)
#pragma unroll
      for (int r = 0; r < 4; ++r) {
        const int row = m0 + (wm << 6) + (mi << 4) + (g4 << 2) + r;
        Y[(size_t)row * DMODEL + col] = acc[mi][ni][r] + bv4;
      }
  }
}

// ---------------------------------------------------------------------------
// MFMA flash attention (r13 structure, exp2f -> raw v_exp_f32):
// 512 thr = 8 waves x 16 q-rows, 4 waves/SIMD; permlane reg-P butterfly,
// no P-LDS; swapped QK^T, defer-max THR=8, single-barrier K/V dbuf, T14
// prefetch, setprio, V XOR-scatter staging.
// Grid: (SEQ/128, NH, BATCH) = 512 blocks, 512 thr.
// ---------------------------------------------------------------------------
__global__ __launch_bounds__(512, 4) void attn_mfma(
    const ushort* __restrict__ Q, const ushort* __restrict__ K,
    const ushort* __restrict__ V, ushort* __restrict__ O) {
  __shared__ ushort Klds[2][64][72];
  __shared__ ushort Vlds[2][64][72];

  const int tid = threadIdx.x;
  const int lane = tid & 63;
  const int wv = tid >> 6;      // wave 0..7
  const int m16 = lane & 15;
  const int g4 = lane >> 4;     // 0..3
  const int b = blockIdx.z;
  const int h = blockIdx.y;
  const int q0 = (blockIdx.x << 7) + (wv << 4);  // wave's 16-row q base

  const size_t base = ((size_t)b * SEQ) * DMODEL + h * DHEAD;  // elem offset

  // --- Q fragments (2 k-steps of 32 over DHEAD=64), rows = m16 ---
  short8 qf[2];
  {
    const ushort* qp = Q + base + (size_t)(q0 + m16) * DMODEL + (g4 << 3);
    qf[0] = *(const short8*)(qp);
    qf[1] = *(const short8*)(qp + 32);
  }

  f32x4 oacc[4];  // [dt]: col d = dt*16+m16, rows q = 4g4 + r
#pragma unroll
  for (int dt = 0; dt < 4; ++dt) oacc[dt] = (f32x4){0.f, 0.f, 0.f, 0.f};
  float mrow = -1e30f;  // running max for q = m16 (log2 domain)
  float lsum = 0.f;     // lane-partial denominator

  // staging map: 512 threads, key = tid>>3 (64), seg = tid&7
  const int skey = tid >> 3;
  const int sseg = tid & 7;
  const ushort* kgp = K + base + (size_t)skey * DMODEL + (sseg << 3);
  const ushort* vgp = V + base + (size_t)skey * DMODEL + (sseg << 3);
  const int vswz_key = skey ^ (sseg << 3);  // conflict-free u16 scatter

  // T14: tile-0 loads issued long before first use
  short8 kvec = *(const short8*)(kgp);
  short8 vvec = *(const short8*)(vgp);

  int p = 0;
  for (int kt = 0; kt < SEQ / 64; ++kt) {
    // stage tile kt into buffer p
    *(short8*)&Klds[p][skey][sseg << 3] = kvec;
#pragma unroll
    for (int i = 0; i < 8; ++i)
      Vlds[p][(sseg << 3) + i][vswz_key] = ((const ushort*)&vvec)[i];
    __syncthreads();  // the only barrier per tile (dbuf)
    // T14: issue next tile's global loads; latency hides under compute
    if (kt + 1 < SEQ / 64) {
      const size_t koff = (size_t)(kt + 1) * 64 * DMODEL;
      kvec = *(const short8*)(kgp + koff);
      vvec = *(const short8*)(vgp + koff);
    }

    // --- S^T = K * Q^T : s[kt2][r] = S[key=16*kt2+4*g4+r][q=m16] ---
    f32x4 s[4];
#pragma unroll
    for (int kt2 = 0; kt2 < 4; ++kt2) s[kt2] = (f32x4){0.f, 0.f, 0.f, 0.f};
    __builtin_amdgcn_s_setprio(1);
#pragma unroll
    for (int ks = 0; ks < 2; ++ks) {
#pragma unroll
      for (int kt2 = 0; kt2 < 4; ++kt2) {
        const short8 kf =
            *(const short8*)&Klds[p][(kt2 << 4) + m16][(ks << 5) + (g4 << 3)];
        s[kt2] =
            __builtin_amdgcn_mfma_f32_16x16x32_bf16(kf, qf[ks], s[kt2], 0, 0, 0);
      }
    }
    __builtin_amdgcn_s_setprio(0);

    // --- online softmax for q = m16 (exp2 domain, raw v_exp_f32) ---
    float t0 = fmaxf(fmaxf(s[0][0], s[0][1]), fmaxf(s[0][2], s[0][3]));
    float t1 = fmaxf(fmaxf(s[1][0], s[1][1]), fmaxf(s[1][2], s[1][3]));
    float t2 = fmaxf(fmaxf(s[2][0], s[2][1]), fmaxf(s[2][2], s[2][3]));
    float t3 = fmaxf(fmaxf(s[3][0], s[3][1]), fmaxf(s[3][2], s[3][3]));
    float tred = fmaxf(fmaxf(t0, t1), fmaxf(t2, t3));
    tred = fmaxf(tred, __shfl_xor(tred, 16));
    tred = fmaxf(tred, __shfl_xor(tred, 32));
    // T13 defer-max: only rescale when the max grew by more than 8
    if (!__all(tred <= mrow + 8.0f)) {
      const float mnew = fmaxf(mrow, tred);
      const float corr = exp2_hw(mrow - mnew);
      lsum *= corr;
      const float cb0 = __shfl(corr, (g4 << 2) + 0);
      const float cb1 = __shfl(corr, (g4 << 2) + 1);
      const float cb2 = __shfl(corr, (g4 << 2) + 2);
      const float cb3 = __shfl(corr, (g4 << 2) + 3);
#pragma unroll
      for (int dt = 0; dt < 4; ++dt) {
        oacc[dt][0] *= cb0; oacc[dt][1] *= cb1;
        oacc[dt][2] *= cb2; oacc[dt][3] *= cb3;
      }
      mrow = mnew;
    }
    float ps = 0.f;
#pragma unroll
    for (int kt2 = 0; kt2 < 4; ++kt2)
#pragma unroll
      for (int r = 0; r < 4; ++r) {
        const float pv = exp2_hw(s[kt2][r] - mrow);
        s[kt2][r] = pv;
        ps += pv;
      }
    lsum += ps;

    // --- P -> PV A-fragment, fully in registers (validated r12/r13) ---
    // pack: W[2*kt2+h] = bf16 pair = key-pair KP = 8*kt2 + 2*g4 + h
    unsigned int W0 = cvtpk(s[0][0], s[0][1]);
    unsigned int W1 = cvtpk(s[0][2], s[0][3]);
    unsigned int W2 = cvtpk(s[1][0], s[1][1]);
    unsigned int W3 = cvtpk(s[1][2], s[1][3]);
    unsigned int W4 = cvtpk(s[2][0], s[2][1]);
    unsigned int W5 = cvtpk(s[2][2], s[2][3]);
    unsigned int W6 = cvtpk(s[3][0], s[3][1]);
    unsigned int W7 = cvtpk(s[3][2], s[3][3]);
    // stage A: swap reg-bit(k3) <-> lane-bit5
    P32SWAP(W0, W2);
    P32SWAP(W1, W3);
    P32SWAP(W4, W6);
    P32SWAP(W5, W7);
    // stage B: swap reg-bit(k2) <-> lane-bit4
    P16SWAP(W0, W2);
    P16SWAP(W1, W3);
    P16SWAP(W4, W6);
    P16SWAP(W5, W7);
    union { unsigned int u[4]; short8 v; } u0, u1;
    u0.u[0] = W0; u0.u[1] = W1; u0.u[2] = W2; u0.u[3] = W3;
    u1.u[0] = W4; u1.u[1] = W5; u1.u[2] = W6; u1.u[3] = W7;

    // --- O += P * V ---
    __builtin_amdgcn_s_setprio(1);
#pragma unroll
    for (int dt = 0; dt < 4; ++dt) {
      const int d = (dt << 4) + m16;
      const int swz = (d >> 3) << 3;
      const short8 vf0 = *(const short8*)&Vlds[p][d][(g4 << 3) ^ swz];
      oacc[dt] = __builtin_amdgcn_mfma_f32_16x16x32_bf16(
          u0.v, vf0, oacc[dt], 0, 0, 0);
      const short8 vf1 = *(const short8*)&Vlds[p][d][(32 + (g4 << 3)) ^ swz];
      oacc[dt] = __builtin_amdgcn_mfma_f32_16x16x32_bf16(
          u1.v, vf1, oacc[dt], 0, 0, 0);
    }
    __builtin_amdgcn_s_setprio(0);
    p ^= 1;
  }

  // --- epilogue: reduce lsum across the 4 q-column copies, normalize ---
  lsum += __shfl_xor(lsum, 16);
  lsum += __shfl_xor(lsum, 32);
  const float inv = 1.0f / lsum;  // for q = m16, in all 4 g4 copies
  const float inv0 = __shfl(inv, (g4 << 2) + 0);
  const float inv1 = __shfl(inv, (g4 << 2) + 1);
  const float inv2 = __shfl(inv, (g4 << 2) + 2);
  const float inv3 = __shfl(inv, (g4 << 2) + 3);
  const float invr[4] = {inv0, inv1, inv2, inv3};
#pragma unroll
  for (int r = 0; r < 4; ++r) {
    const size_t row = (size_t)(q0 + (g4 << 2) + r);
    ushort* op = O + ((size_t)b * SEQ + row) * DMODEL + h * DHEAD + m16;
#pragma unroll
    for (int dt = 0; dt < 4; ++dt) op[dt << 4] = f2bf(oacc[dt][r] * invr[r]);
  }
}

// ---------------------------------------------------------------------------
extern "C" void kernel_launch(void* const* d_in, const int* in_sizes, int n_in,
                              void* d_out, int out_size, void* d_ws,
                              size_t ws_size, hipStream_t stream) {
  const float* hs = (const float*)d_in[0];
  const float* wq = (const float*)d_in[1];
  const float* bq = (const float*)d_in[2];
  const float* wk = (const float*)d_in[3];
  const float* bk = (const float*)d_in[4];
  const float* wv = (const float*)d_in[5];
  const float* bv = (const float*)d_in[6];
  const float* wo = (const float*)d_in[7];
  const float* bo = (const float*)d_in[8];
  float* out = (float*)d_out;

  // ws layout (ushort elems): hsb 4M | wqb/wkb/wvb/wob 1M each | Qb/Kb/Vb 4M
  // | Ab 4M  -> 24M ushorts = 48 MiB
  const size_t elems = (size_t)BATCH * SEQ * DMODEL;  // 4M
  const size_t welems = (size_t)DMODEL * DMODEL;      // 1M
  ushort* hsb = (ushort*)d_ws;
  ushort* wqb = hsb + elems;
  ushort* wkb = wqb + welems;
  ushort* wvb = wkb + welems;
  ushort* wob = wvb + welems;
  ushort* Qb = wob + welems;
  ushort* Kb = Qb + elems;
  ushort* Vb = Kb + elems;
  ushort* Ab = Vb + elems;

  cast_all<<<dim3((int)(elems / (256 * 8)), 5, 1), 256, 0, stream>>>(
      hs, wq, wk, wv, wo, hsb, wqb, wkb, wvb, wob);
  qkv_mfma<<<dim3(DMODEL / 128, (BATCH * SEQ) / 128, 3), 512, 0, stream>>>(
      hsb, wqb, wkb, wvb, bq, bk, bv, Qb, Kb, Vb);
  attn_mfma<<<dim3(SEQ / 128, NH, BATCH), 512, 0, stream>>>(Qb, Kb, Vb, Ab);
  oproj_mfma<<<dim3(DMODEL / 128, (BATCH * SEQ) / 128, 1), 512, 0, stream>>>(
      Ab, wob, bo, out);
}